// Round 1
// baseline (120.240 us; speedup 1.0000x reference)
//
#include <hip/hip_runtime.h>

static constexpr int T_LEN   = 16384;
static constexpr int CHUNKS  = 8;      // blocks per sample
static constexpr int THREADS = 256;

__device__ __forceinline__ float pow5f(float x) { float x2 = x * x; return x2 * x2 * x; }

__global__ __launch_bounds__(THREADS) void focal_partial(
    const float* __restrict__ cls,   // [B, T, 2]
    const float* __restrict__ reg,   // [B, T, 1]
    const float* __restrict__ ann,   // [B, 3, T]
    float* __restrict__ ws,          // [B, 4] accumulators
    int T)
{
    const int b     = blockIdx.x;
    const int chunk = blockIdx.y;
    const int CHUNK = T / CHUNKS;
    const float rn_scale = 22050.0f / ((float)T * 256.0f);  // SR / (T * TARGET_FACTOR)

    const float* a0 = ann + (size_t)b * 3 * T;
    const float* a1 = a0 + T;
    const float* a2 = a0 + 2 * T;
    const float* rg = reg + (size_t)b * T;
    const float* cl = cls + (size_t)b * T * 2;

    float fsum = 0.f, npos = 0.f, rsum = 0.f, kcnt = 0.f;
    const int tid = threadIdx.x;

    #pragma unroll
    for (int g = 0; g < (T_LEN / CHUNKS) / (THREADS * 4); ++g) {
        const int i = chunk * CHUNK + g * THREADS * 4 + tid * 4;

        const float4 v0  = *(const float4*)(a0 + i);
        const float4 v1  = *(const float4*)(a1 + i);
        const float4 v2  = *(const float4*)(a2 + i);
        const float4 vr  = *(const float4*)(rg + i);
        const float4 vc0 = *(const float4*)(cl + 2 * i);
        const float4 vc1 = *(const float4*)(cl + 2 * i + 4);

        const float A0[4] = {v0.x, v0.y, v0.z, v0.w};
        const float A1[4] = {v1.x, v1.y, v1.z, v1.w};
        const float A2[4] = {v2.x, v2.y, v2.z, v2.w};
        float       R[5]  = {vr.x, vr.y, vr.z, vr.w, 0.f};
        const float C[8]  = {vc0.x, vc0.y, vc0.z, vc0.w, vc1.x, vc1.y, vc1.z, vc1.w};

        // adjusted beat mask for the regression part:
        //   pos[T-2] = last_is_beat ? 1 : ann0[T-2];  pos[T-1] = 0 (ann0 is binary)
        float P[4] = {A0[0], A0[1], A0[2], A0[3]};
        if (i + 4 == T) {                       // the group containing T-4..T-1
            const bool last_beat = (A0[3] == 1.0f);
            P[2] = last_beat ? 1.0f : A0[2];
            P[3] = 0.0f;
        }
        // right neighbor of element i+3 (only group-tail element needing reg[i+4]);
        // the last group has P[3]==0, so the load is always in-bounds.
        if (P[3] != 0.0f) R[4] = rg[i + 4];

        #pragma unroll
        for (int j = 0; j < 4; ++j) {
            const float a0j = A0[j];
            npos += a0j;
            const bool beat = (a0j   == 1.0f);
            const bool down = (A1[j] == 1.0f);
            const bool l0 = beat && down;
            const bool l1 = beat && !down;
            const float c0 = fminf(fmaxf(C[2 * j],     1e-4f), 1.0f - 1e-4f);
            const float c1 = fminf(fmaxf(C[2 * j + 1], 1e-4f), 1.0f - 1e-4f);
            fsum += l0 ? 0.25f * pow5f(1.f - c0) * (-__logf(c0))
                       : 0.75f * pow5f(c0)       * (-__logf(1.f - c0));
            fsum += l1 ? 0.25f * pow5f(1.f - c1) * (-__logf(c1))
                       : 0.75f * pow5f(c1)       * (-__logf(1.f - c1));
            if (P[j] != 0.0f) {
                const float rn = A2[j] * rn_scale;
                const float dl = rn - R[j];
                const float dr = rn - R[j + 1];
                rsum += 0.5f * (dl * dl + dr * dr);
                kcnt += 1.0f;
            }
        }
    }

    // wave(64) shuffle reduction
    #pragma unroll
    for (int off = 32; off > 0; off >>= 1) {
        fsum += __shfl_down(fsum, off);
        npos += __shfl_down(npos, off);
        rsum += __shfl_down(rsum, off);
        kcnt += __shfl_down(kcnt, off);
    }
    __shared__ float sf[4], sn[4], sr[4], sk[4];
    const int wave = tid >> 6;
    if ((tid & 63) == 0) { sf[wave] = fsum; sn[wave] = npos; sr[wave] = rsum; sk[wave] = kcnt; }
    __syncthreads();
    if (tid == 0) {
        atomicAdd(&ws[b * 4 + 0], sf[0] + sf[1] + sf[2] + sf[3]);
        atomicAdd(&ws[b * 4 + 1], sn[0] + sn[1] + sn[2] + sn[3]);
        atomicAdd(&ws[b * 4 + 2], sr[0] + sr[1] + sr[2] + sr[3]);
        atomicAdd(&ws[b * 4 + 3], sk[0] + sk[1] + sk[2] + sk[3]);
    }
}

__global__ __launch_bounds__(256) void focal_finalize(
    const float* __restrict__ ws, float* __restrict__ out, int B)
{
    const int tid = threadIdx.x;
    float cv = 0.f, rv = 0.f;
    if (tid < B) {
        const float F = ws[tid * 4 + 0];
        const float N = ws[tid * 4 + 1];
        const float S = ws[tid * 4 + 2];
        const float K = ws[tid * 4 + 3];
        cv = F / N * 10.0f;
        rv = S / K * 10.0f;
    }
    #pragma unroll
    for (int off = 32; off > 0; off >>= 1) {
        cv += __shfl_down(cv, off);
        rv += __shfl_down(rv, off);
    }
    __shared__ float sc[4], sr[4];
    if ((tid & 63) == 0) { sc[tid >> 6] = cv; sr[tid >> 6] = rv; }
    __syncthreads();
    if (tid == 0) {
        out[0] = (sc[0] + sc[1] + sc[2] + sc[3]) / (float)B;
        out[1] = (sr[0] + sr[1] + sr[2] + sr[3]) / (float)B;
    }
}

extern "C" void kernel_launch(void* const* d_in, const int* in_sizes, int n_in,
                              void* d_out, int out_size, void* d_ws, size_t ws_size,
                              hipStream_t stream)
{
    const float* cls = (const float*)d_in[0];
    const float* reg = (const float*)d_in[1];
    const float* ann = (const float*)d_in[2];
    float* out = (float*)d_out;
    float* ws  = (float*)d_ws;

    const int T = T_LEN;
    const int B = in_sizes[1] / T;   // regressions is [B, T, 1]

    hipMemsetAsync(d_ws, 0, (size_t)B * 4 * sizeof(float), stream);
    dim3 grid(B, CHUNKS);
    focal_partial<<<grid, THREADS, 0, stream>>>(cls, reg, ann, ws, T);
    focal_finalize<<<1, 256, 0, stream>>>(ws, out, B);
}

// Round 2
// 117.773 us; speedup vs baseline: 1.0209x; 1.0209x over previous
//
#include <hip/hip_runtime.h>

static constexpr int T_LEN   = 16384;
static constexpr int CHUNKS  = 8;      // blocks per sample
static constexpr int THREADS = 256;

__device__ __forceinline__ float pow5f(float x) { float x2 = x * x; return x2 * x2 * x; }

__global__ __launch_bounds__(THREADS) void focal_partial(
    const float* __restrict__ cls,   // [B, T, 2]
    const float* __restrict__ reg,   // [B, T, 1]
    const float* __restrict__ ann,   // [B, 3, T]
    float4* __restrict__ ws4,        // [B * CHUNKS] partial {fsum, npos, rsum, kcnt}
    int T)
{
    const int b     = blockIdx.x;
    const int chunk = blockIdx.y;
    const int CHUNK = T / CHUNKS;
    const float rn_scale = 22050.0f / ((float)T * 256.0f);  // SR / (T * TARGET_FACTOR)

    const float* a0 = ann + (size_t)b * 3 * T;
    const float* a1 = a0 + T;
    const float* a2 = a0 + 2 * T;
    const float* rg = reg + (size_t)b * T;
    const float* cl = cls + (size_t)b * T * 2;

    float fsum = 0.f, npos = 0.f, rsum = 0.f, kcnt = 0.f;
    const int tid = threadIdx.x;

    #pragma unroll
    for (int g = 0; g < (T_LEN / CHUNKS) / (THREADS * 4); ++g) {
        const int i = chunk * CHUNK + g * THREADS * 4 + tid * 4;

        const float4 v0  = *(const float4*)(a0 + i);
        const float4 v1  = *(const float4*)(a1 + i);
        const float4 v2  = *(const float4*)(a2 + i);
        const float4 vr  = *(const float4*)(rg + i);
        const float4 vc0 = *(const float4*)(cl + 2 * i);
        const float4 vc1 = *(const float4*)(cl + 2 * i + 4);

        const float A0[4] = {v0.x, v0.y, v0.z, v0.w};
        const float A1[4] = {v1.x, v1.y, v1.z, v1.w};
        const float A2[4] = {v2.x, v2.y, v2.z, v2.w};
        float       R[5]  = {vr.x, vr.y, vr.z, vr.w, 0.f};
        const float C[8]  = {vc0.x, vc0.y, vc0.z, vc0.w, vc1.x, vc1.y, vc1.z, vc1.w};

        // adjusted beat mask for the regression part:
        //   pos[T-2] = last_is_beat ? 1 : ann0[T-2];  pos[T-1] = 0 (ann0 is binary)
        float P[4] = {A0[0], A0[1], A0[2], A0[3]};
        if (i + 4 == T) {                       // the group containing T-4..T-1
            const bool last_beat = (A0[3] == 1.0f);
            P[2] = last_beat ? 1.0f : A0[2];
            P[3] = 0.0f;
        }
        // right neighbor of element i+3 (only group-tail element needing reg[i+4]);
        // the last group has P[3]==0, so the load is always in-bounds.
        if (P[3] != 0.0f) R[4] = rg[i + 4];

        #pragma unroll
        for (int j = 0; j < 4; ++j) {
            const float a0j = A0[j];
            npos += a0j;
            const bool beat = (a0j   == 1.0f);
            const bool down = (A1[j] == 1.0f);
            const bool l0 = beat && down;
            const bool l1 = beat && !down;
            // one-sided focal form: with t = lab ? 1-c : c,
            //   term = (lab ? 0.25 : 0.75) * t^5 * (-log(1-t))
            {
                const float c = fminf(fmaxf(C[2 * j], 1e-4f), 1.0f - 1e-4f);
                const float t = l0 ? 1.f - c : c;
                const float af = l0 ? 0.25f : 0.75f;
                fsum += af * pow5f(t) * (-__logf(1.f - t));
            }
            {
                const float c = fminf(fmaxf(C[2 * j + 1], 1e-4f), 1.0f - 1e-4f);
                const float t = l1 ? 1.f - c : c;
                const float af = l1 ? 0.25f : 0.75f;
                fsum += af * pow5f(t) * (-__logf(1.f - t));
            }
            if (P[j] != 0.0f) {
                const float rn = A2[j] * rn_scale;
                const float dl = rn - R[j];
                const float dr = rn - R[j + 1];
                rsum += 0.5f * (dl * dl + dr * dr);
                kcnt += 1.0f;
            }
        }
    }

    // wave(64) shuffle reduction
    #pragma unroll
    for (int off = 32; off > 0; off >>= 1) {
        fsum += __shfl_down(fsum, off);
        npos += __shfl_down(npos, off);
        rsum += __shfl_down(rsum, off);
        kcnt += __shfl_down(kcnt, off);
    }
    __shared__ float sf[4], sn[4], sr[4], sk[4];
    const int wave = tid >> 6;
    if ((tid & 63) == 0) { sf[wave] = fsum; sn[wave] = npos; sr[wave] = rsum; sk[wave] = kcnt; }
    __syncthreads();
    if (tid == 0) {
        // direct store of this block's partial — no memset / atomics needed,
        // the 0xAA poison in d_ws is fully overwritten every launch.
        ws4[b * CHUNKS + chunk] = make_float4(
            sf[0] + sf[1] + sf[2] + sf[3],
            sn[0] + sn[1] + sn[2] + sn[3],
            sr[0] + sr[1] + sr[2] + sr[3],
            sk[0] + sk[1] + sk[2] + sk[3]);
    }
}

__global__ __launch_bounds__(256) void focal_finalize(
    const float4* __restrict__ ws4, float* __restrict__ out, int B)
{
    const int tid = threadIdx.x;
    float cv = 0.f, rv = 0.f;
    for (int b = tid; b < B; b += 256) {
        float F = 0.f, N = 0.f, S = 0.f, K = 0.f;
        #pragma unroll
        for (int c = 0; c < CHUNKS; ++c) {
            const float4 v = ws4[b * CHUNKS + c];
            F += v.x; N += v.y; S += v.z; K += v.w;
        }
        cv += F / N * 10.0f;
        rv += S / K * 10.0f;
    }
    #pragma unroll
    for (int off = 32; off > 0; off >>= 1) {
        cv += __shfl_down(cv, off);
        rv += __shfl_down(rv, off);
    }
    __shared__ float sc[4], sr[4];
    if ((tid & 63) == 0) { sc[tid >> 6] = cv; sr[tid >> 6] = rv; }
    __syncthreads();
    if (tid == 0) {
        out[0] = (sc[0] + sc[1] + sc[2] + sc[3]) / (float)B;
        out[1] = (sr[0] + sr[1] + sr[2] + sr[3]) / (float)B;
    }
}

extern "C" void kernel_launch(void* const* d_in, const int* in_sizes, int n_in,
                              void* d_out, int out_size, void* d_ws, size_t ws_size,
                              hipStream_t stream)
{
    const float* cls = (const float*)d_in[0];
    const float* reg = (const float*)d_in[1];
    const float* ann = (const float*)d_in[2];
    float* out = (float*)d_out;
    float4* ws4 = (float4*)d_ws;

    const int T = T_LEN;
    const int B = in_sizes[1] / T;   // regressions is [B, T, 1]

    dim3 grid(B, CHUNKS);
    focal_partial<<<grid, THREADS, 0, stream>>>(cls, reg, ann, ws4, T);
    focal_finalize<<<1, 256, 0, stream>>>(ws4, out, B);
}